// Round 10
// baseline (97.528 us; speedup 1.0000x reference)
//
#include <hip/hip_runtime.h>
#include <cstdint>

#define P 7
#define PP 49
#define IMG 64
#define PIX 4096
#define XSTR 72    // LDS row stride: 288B = 16B-aligned rows -> b128 merges
#define XROWS 28   // xs tile rows: x rows q*16-6 .. q*16+21
#define MROWS 22   // ms tile rows: maps1 rows q*16-3 .. q*16+18

// ---- 7x10 window in 70 named scalars (no arrays -> no scratch) ----
#define DECLW \
    float x00,x01,x02,x03,x04,x05,x06,x07,x08,x09; \
    float x10,x11,x12,x13,x14,x15,x16,x17,x18,x19; \
    float x20,x21,x22,x23,x24,x25,x26,x27,x28,x29; \
    float x30,x31,x32,x33,x34,x35,x36,x37,x38,x39; \
    float x40,x41,x42,x43,x44,x45,x46,x47,x48,x49; \
    float x50,x51,x52,x53,x54,x55,x56,x57,x58,x59; \
    float x60,x61,x62,x63,x64,x65,x66,x67,x68,x69;

#define LDROW(i, BP) \
    x##i##0=(BP)[0]; x##i##1=(BP)[1]; x##i##2=(BP)[2]; x##i##3=(BP)[3]; \
    x##i##4=(BP)[4]; x##i##5=(BP)[5]; x##i##6=(BP)[6]; x##i##7=(BP)[7]; \
    x##i##8=(BP)[8]; x##i##9=(BP)[9];

#define LDWIN(B) \
    LDROW(0,(B)+0*XSTR) LDROW(1,(B)+1*XSTR) LDROW(2,(B)+2*XSTR) \
    LDROW(3,(B)+3*XSTR) LDROW(4,(B)+4*XSTR) LDROW(5,(B)+5*XSTR) \
    LDROW(6,(B)+6*XSTR)

// per-row window sums: px p uses cols p..p+6, each accumulated j-ascending
#define SUMROW(i) \
    s0+=x##i##0; s1+=x##i##1; s2+=x##i##2; s3+=x##i##3; \
    s0+=x##i##1; s1+=x##i##2; s2+=x##i##3; s3+=x##i##4; \
    s0+=x##i##2; s1+=x##i##3; s2+=x##i##4; s3+=x##i##5; \
    s0+=x##i##3; s1+=x##i##4; s2+=x##i##5; s3+=x##i##6; \
    s0+=x##i##4; s1+=x##i##5; s2+=x##i##6; s3+=x##i##7; \
    s0+=x##i##5; s1+=x##i##6; s2+=x##i##7; s3+=x##i##8; \
    s0+=x##i##6; s1+=x##i##7; s2+=x##i##8; s3+=x##i##9;

#define SUMALL SUMROW(0) SUMROW(1) SUMROW(2) SUMROW(3) SUMROW(4) SUMROW(5) SUMROW(6)

// ---- stage 1: one filter, weight broadcast from LDS; fence per tap ----
// sched_barrier(0x3): only ALU/VALU may cross -> ds_reads stay pinned to
// their tap (bounded weight liveness), fmas may drift to hide DS latency.
#define S1TAP(i,J,JA,JB,JC) { const float w = w1s[(i)*7+(J)]; \
    a0 = fmaf(w, x##i##J  - mu0, a0); a1 = fmaf(w, x##i##JA - mu1, a1); \
    a2 = fmaf(w, x##i##JB - mu2, a2); a3 = fmaf(w, x##i##JC - mu3, a3); \
    __builtin_amdgcn_sched_barrier(0x3); }
#define S1ROW(i) \
    S1TAP(i,0,1,2,3) S1TAP(i,1,2,3,4) S1TAP(i,2,3,4,5) S1TAP(i,3,4,5,6) \
    S1TAP(i,4,5,6,7) S1TAP(i,5,6,7,8) S1TAP(i,6,7,8,9)
#define S1ALL S1ROW(0) S1ROW(1) S1ROW(2) S1ROW(3) S1ROW(4) S1ROW(5) S1ROW(6)

// ---- stage 2: 8 filters via two 16B LDS broadcasts per tap; fence per tap --
// per-pixel chains: filters ascending, k ascending -- identical op order.
#define S2TAP(i,J,JA,JB,JC) { \
    const float t0 = x##i##J  - mu0, t1 = x##i##JA - mu1; \
    const float t2 = x##i##JB - mu2, t3 = x##i##JC - mu3; \
    const float4 wA = *(const float4*)&w2s[((i)*7+(J))*8]; \
    const float4 wB = *(const float4*)&w2s[((i)*7+(J))*8 + 4]; \
    a0=fmaf(wA.x,t0,a0); b0=fmaf(wA.x,t1,b0); c0=fmaf(wA.x,t2,c0); d0=fmaf(wA.x,t3,d0); \
    a1=fmaf(wA.y,t0,a1); b1=fmaf(wA.y,t1,b1); c1=fmaf(wA.y,t2,c1); d1=fmaf(wA.y,t3,d1); \
    a2=fmaf(wA.z,t0,a2); b2=fmaf(wA.z,t1,b2); c2=fmaf(wA.z,t2,c2); d2=fmaf(wA.z,t3,d2); \
    a3=fmaf(wA.w,t0,a3); b3=fmaf(wA.w,t1,b3); c3=fmaf(wA.w,t2,c3); d3=fmaf(wA.w,t3,d3); \
    a4=fmaf(wB.x,t0,a4); b4=fmaf(wB.x,t1,b4); c4=fmaf(wB.x,t2,c4); d4=fmaf(wB.x,t3,d4); \
    a5=fmaf(wB.y,t0,a5); b5=fmaf(wB.y,t1,b5); c5=fmaf(wB.y,t2,c5); d5=fmaf(wB.y,t3,d5); \
    a6=fmaf(wB.z,t0,a6); b6=fmaf(wB.z,t1,b6); c6=fmaf(wB.z,t2,c6); d6=fmaf(wB.z,t3,d6); \
    a7=fmaf(wB.w,t0,a7); b7=fmaf(wB.w,t1,b7); c7=fmaf(wB.w,t2,c7); d7=fmaf(wB.w,t3,d7); \
    __builtin_amdgcn_sched_barrier(0x3); }
#define S2ROW(i) \
    S2TAP(i,0,1,2,3) S2TAP(i,1,2,3,4) S2TAP(i,2,3,4,5) S2TAP(i,3,4,5,6) \
    S2TAP(i,4,5,6,7) S2TAP(i,5,6,7,8) S2TAP(i,6,7,8,9)
#define S2ALL S2ROW(0) S2ROW(1) S2ROW(2) S2ROW(3) S2ROW(4) S2ROW(5) S2ROW(6)

// ---------------------------------------------------------------------------
// One block per (channel, row-quarter): 2048 blocks x 256 threads.
// r9 structure; change: 4-px strips (7x10 window) + XSTR=72 for 16B-aligned
// LDS rows (b128 merges). Halves DS instrs/pixel. launch_bounds(256,3) gives
// 168-VGPR cap for the ~125-reg live set.
// ---------------------------------------------------------------------------
__global__ __launch_bounds__(256, 3) void stage_kernel(
    const float* __restrict__ x,    // [64][64][64]
    const float* __restrict__ W1,   // [49][8]
    const float* __restrict__ W2,   // [49][8]
    uint8_t* __restrict__ codes)    // [512][4096]
{
    __shared__ __align__(16) float xs[XROWS * XSTR];  // x rows q16-6..q16+21, cols -3..68
    __shared__ __align__(16) float ms[MROWS * XSTR];  // maps1 rows q16-3..q16+18, cols -3..68
    __shared__ float w1s[PP];
    __shared__ __align__(16) float w2s[PP * 8];

    const int b    = blockIdx.x;
    const int ch   = b >> 2;
    const int q16  = (b & 3) * 16;
    const int l    = ch >> 6;
    const int img  = ch & 63;
    const int tid  = threadIdx.x;

    // stage weights into LDS (all threads cover all elements)
    if (tid < PP) w1s[tid] = W1[tid * 8 + l];
    #pragma unroll 1
    for (int i = tid; i < PP * 8; i += 256) w2s[i] = W2[i];

    // zero ms (stage-2 SAME padding: pad cols + out-of-image rows stay 0)
    #pragma unroll 1
    for (int i = tid; i < MROWS * XSTR; i += 256) ms[i] = 0.f;

    // load xs zero-padded
    const float* xb = x + (size_t)img * PIX;
    #pragma unroll 1
    for (int idx = tid; idx < XROWS * XSTR; idx += 256) {
        int r  = idx / XSTR, c = idx - r * XSTR;
        int gr = q16 - 6 + r, gc = c - 3;
        float v = 0.f;
        if (gr >= 0 && gr < IMG && gc >= 0 && gc < IMG)
            v = xb[gr * IMG + gc];
        xs[idx] = v;
    }
    __syncthreads();

    // ---- stage 1: 22 rows x 16 col-strips = 352 strips (4 px each) ----
    #pragma unroll 1
    for (int it = 0; it < 2; ++it) {
        int s = tid + it * 256;
        if (s < MROWS * 16) {
            const int row = s >> 4;           // 0..21
            const int cs4 = (s & 15) * 4;     // 0..60
            const float* bp = &xs[row * XSTR + cs4];
            DECLW
            LDWIN(bp)
            float s0 = 0.f, s1 = 0.f, s2 = 0.f, s3 = 0.f;
            SUMALL
            const float mu0 = s0 / 49.0f, mu1 = s1 / 49.0f;
            const float mu2 = s2 / 49.0f, mu3 = s3 / 49.0f;
            float a0 = 0.f, a1 = 0.f, a2 = 0.f, a3 = 0.f;
            S1ALL
            const int gm = q16 - 3 + row;
            const bool in_img = (gm >= 0) && (gm < IMG);
            float* mp = &ms[row * XSTR + 3 + cs4];
            mp[0] = in_img ? a0 : 0.f;
            mp[1] = in_img ? a1 : 0.f;
            mp[2] = in_img ? a2 : 0.f;
            mp[3] = in_img ? a3 : 0.f;
        }
    }
    __syncthreads();

    // ---- stage 2 + code bits: 16 rows x 16 col-strips = 256 strips ----
    {
        const int s   = tid;
        const int rr  = s >> 4;               // 0..15
        const int cs4 = (s & 15) * 4;         // 0..60
        const float* bp = &ms[rr * XSTR + cs4];
        DECLW
        LDWIN(bp)
        float s0 = 0.f, s1 = 0.f, s2 = 0.f, s3 = 0.f;
        SUMALL
        const float mu0 = s0 / 49.0f, mu1 = s1 / 49.0f;
        const float mu2 = s2 / 49.0f, mu3 = s3 / 49.0f;
        float a0=0.f,a1=0.f,a2=0.f,a3=0.f,a4=0.f,a5=0.f,a6=0.f,a7=0.f;
        float b0=0.f,b1=0.f,b2=0.f,b3=0.f,b4=0.f,b5=0.f,b6=0.f,b7=0.f;
        float c0=0.f,c1=0.f,c2=0.f,c3=0.f,c4=0.f,c5=0.f,c6=0.f,c7=0.f;
        float d0=0.f,d1=0.f,d2=0.f,d3=0.f,d4=0.f,d5=0.f,d6=0.f,d7=0.f;
        S2ALL
        uint32_t k0 = 0, k1 = 0, k2 = 0, k3 = 0;
        k0 |= (a0>0.f)?128u:0u; k1 |= (b0>0.f)?128u:0u; k2 |= (c0>0.f)?128u:0u; k3 |= (d0>0.f)?128u:0u;
        k0 |= (a1>0.f)? 64u:0u; k1 |= (b1>0.f)? 64u:0u; k2 |= (c1>0.f)? 64u:0u; k3 |= (d1>0.f)? 64u:0u;
        k0 |= (a2>0.f)? 32u:0u; k1 |= (b2>0.f)? 32u:0u; k2 |= (c2>0.f)? 32u:0u; k3 |= (d2>0.f)? 32u:0u;
        k0 |= (a3>0.f)? 16u:0u; k1 |= (b3>0.f)? 16u:0u; k2 |= (c3>0.f)? 16u:0u; k3 |= (d3>0.f)? 16u:0u;
        k0 |= (a4>0.f)?  8u:0u; k1 |= (b4>0.f)?  8u:0u; k2 |= (c4>0.f)?  8u:0u; k3 |= (d4>0.f)?  8u:0u;
        k0 |= (a5>0.f)?  4u:0u; k1 |= (b5>0.f)?  4u:0u; k2 |= (c5>0.f)?  4u:0u; k3 |= (d5>0.f)?  4u:0u;
        k0 |= (a6>0.f)?  2u:0u; k1 |= (b6>0.f)?  2u:0u; k2 |= (c6>0.f)?  2u:0u; k3 |= (d6>0.f)?  2u:0u;
        k0 |= (a7>0.f)?  1u:0u; k1 |= (b7>0.f)?  1u:0u; k2 |= (c7>0.f)?  1u:0u; k3 |= (d7>0.f)?  1u:0u;
        uint32_t packed = k0 | (k1 << 8) | (k2 << 16) | (k3 << 24);
        *(uint32_t*)(codes + (size_t)ch * PIX + (q16 + rr) * 64 + cs4) = packed;
    }
}

// ---------------------------------------------------------------------------
// Kernel B: histogram + entropy (unchanged, ~4 us)
// ---------------------------------------------------------------------------
#define CPB 32

__global__ __launch_bounds__(256) void hist_kernel(
    const uint8_t* __restrict__ codes,  // [512][4096]
    float* __restrict__ out)            // [49*256][512]
{
    __shared__ uint32_t hist[256 * 33];

    const int bid   = blockIdx.x;       // 0..783
    const int cgrp  = bid & 15;
    const int nb    = bid >> 4;         // 0..48
    const int bi    = nb / 7, bj = nb - bi * 7;
    const int tid   = threadIdx.x;
    const int cbase = cgrp * CPB;

    for (int i = tid; i < 256 * 33; i += 256) hist[i] = 0;
    __syncthreads();

    const int cl  = tid >> 3;           // 0..31
    const int sub = tid & 7;            // 0..7
    const uint8_t* cp = codes + (size_t)(cbase + cl) * PIX;
    #pragma unroll
    for (int rr = 0; rr < 2; ++rr) {
        int row = bi * 8 + (sub * 2 + rr);
        const uint8_t* rp = cp + row * 64 + bj * 8;
        uint64_t v0 = *(const uint64_t*)(rp);
        uint64_t v1 = *(const uint64_t*)(rp + 8);
        #pragma unroll
        for (int t = 0; t < 8; ++t)
            atomicAdd(&hist[(uint32_t)((v0 >> (8 * t)) & 255u) * 33 + cl], 1u);
        #pragma unroll
        for (int t = 0; t < 8; ++t)
            atomicAdd(&hist[(uint32_t)((v1 >> (8 * t)) & 255u) * 33 + cl], 1u);
    }
    __syncthreads();

    const int lane_c = tid & 31;
    const int bin0   = tid >> 5;        // 0..7
    for (int i = 0; i < 32; ++i) {
        int bin = i * 8 + bin0;
        uint32_t cnt = hist[bin * 33 + lane_c];
        float ent = 0.f;
        if (cnt > 0) {
            float pz = (float)cnt * (1.0f / 256.0f);
            ent = -pz * log2f(pz);
        }
        out[((size_t)(nb * 256 + bin)) * 512 + cbase + lane_c] = ent;
    }
}

extern "C" void kernel_launch(void* const* d_in, const int* in_sizes, int n_in,
                              void* d_out, int out_size, void* d_ws, size_t ws_size,
                              hipStream_t stream) {
    const float* x  = (const float*)d_in[0];
    const float* W1 = (const float*)d_in[1];
    const float* W2 = (const float*)d_in[2];
    float* out = (float*)d_out;
    uint8_t* codes = (uint8_t*)d_ws;   // 512*4096 = 2 MB

    stage_kernel<<<2048, 256, 0, stream>>>(x, W1, W2, codes);
    hist_kernel<<<784, 256, 0, stream>>>(codes, out);
}

// Round 11
// 65.826 us; speedup vs baseline: 1.4816x; 1.4816x over previous
//
#include <hip/hip_runtime.h>
#include <cstdint>

#define P 7
#define PP 49
#define IMG 64
#define PIX 4096
#define XSTR 72    // LDS row stride: 288B, 16B-aligned rows -> b128 merging
#define XROWS 28   // xs tile rows: x rows q*16-6 .. q*16+21
#define MROWS 22   // ms tile rows: maps1 rows q*16-3 .. q*16+18

// ---- one 10-float row in reused named scalars (no arrays, low liveness) ----
#define DECLR float r0,r1,r2,r3,r4,r5,r6,r7,r8,r9;
#define LDROW10(BP) \
    r0=(BP)[0]; r1=(BP)[1]; r2=(BP)[2]; r3=(BP)[3]; r4=(BP)[4]; \
    r5=(BP)[5]; r6=(BP)[6]; r7=(BP)[7]; r8=(BP)[8]; r9=(BP)[9];

// per-row window sums: px p uses cols p..p+6, each accumulated j-ascending
// (bit-identical chain order to verified r10)
#define SUMBODY \
    s0+=r0; s1+=r1; s2+=r2; s3+=r3; \
    s0+=r1; s1+=r2; s2+=r3; s3+=r4; \
    s0+=r2; s1+=r3; s2+=r4; s3+=r5; \
    s0+=r3; s1+=r4; s2+=r5; s3+=r6; \
    s0+=r4; s1+=r5; s2+=r6; s3+=r7; \
    s0+=r5; s1+=r6; s2+=r7; s3+=r8; \
    s0+=r6; s1+=r7; s2+=r8; s3+=r9;

// fence: only ALU/VALU may cross -> DS reads stay pinned to their row/tap
// (bounded liveness: this is what keeps the allocator at ~64-80 VGPR)
#define FENCE __builtin_amdgcn_sched_barrier(0x3);

#define SUMR(i, B) { LDROW10((B) + (i)*XSTR) SUMBODY FENCE }
#define SUMALL(B) SUMR(0,B) SUMR(1,B) SUMR(2,B) SUMR(3,B) SUMR(4,B) SUMR(5,B) SUMR(6,B)

// ---- stage 1: one filter, w1 broadcast from LDS; fence per tap ----
#define S1T(i,j,RA,RB,RC,RD) { const float w = w1s[(i)*7+(j)]; \
    a0 = fmaf(w, (RA)-mu0, a0); a1 = fmaf(w, (RB)-mu1, a1); \
    a2 = fmaf(w, (RC)-mu2, a2); a3 = fmaf(w, (RD)-mu3, a3); FENCE }
#define S1ROWS(i, B) { LDROW10((B) + (i)*XSTR) FENCE \
    S1T(i,0,r0,r1,r2,r3) S1T(i,1,r1,r2,r3,r4) S1T(i,2,r2,r3,r4,r5) \
    S1T(i,3,r3,r4,r5,r6) S1T(i,4,r4,r5,r6,r7) S1T(i,5,r5,r6,r7,r8) \
    S1T(i,6,r6,r7,r8,r9) }
#define S1ALL(B) S1ROWS(0,B) S1ROWS(1,B) S1ROWS(2,B) S1ROWS(3,B) \
                 S1ROWS(4,B) S1ROWS(5,B) S1ROWS(6,B)

// ---- stage 2: 8 filters via two 16B LDS broadcasts per tap; fence per tap --
// per-pixel chains: filters ascending, k ascending -- identical to r10
#define S2T(i,j,RA,RB,RC,RD) { \
    const float t0 = (RA)-mu0, t1 = (RB)-mu1, t2 = (RC)-mu2, t3 = (RD)-mu3; \
    const float4 wA = *(const float4*)&w2s[((i)*7+(j))*8]; \
    const float4 wB = *(const float4*)&w2s[((i)*7+(j))*8 + 4]; \
    a0=fmaf(wA.x,t0,a0); b0=fmaf(wA.x,t1,b0); c0=fmaf(wA.x,t2,c0); d0=fmaf(wA.x,t3,d0); \
    a1=fmaf(wA.y,t0,a1); b1=fmaf(wA.y,t1,b1); c1=fmaf(wA.y,t2,c1); d1=fmaf(wA.y,t3,d1); \
    a2=fmaf(wA.z,t0,a2); b2=fmaf(wA.z,t1,b2); c2=fmaf(wA.z,t2,c2); d2=fmaf(wA.z,t3,d2); \
    a3=fmaf(wA.w,t0,a3); b3=fmaf(wA.w,t1,b3); c3=fmaf(wA.w,t2,c3); d3=fmaf(wA.w,t3,d3); \
    a4=fmaf(wB.x,t0,a4); b4=fmaf(wB.x,t1,b4); c4=fmaf(wB.x,t2,c4); d4=fmaf(wB.x,t3,d4); \
    a5=fmaf(wB.y,t0,a5); b5=fmaf(wB.y,t1,b5); c5=fmaf(wB.y,t2,c5); d5=fmaf(wB.y,t3,d5); \
    a6=fmaf(wB.z,t0,a6); b6=fmaf(wB.z,t1,b6); c6=fmaf(wB.z,t2,c6); d6=fmaf(wB.z,t3,d6); \
    a7=fmaf(wB.w,t0,a7); b7=fmaf(wB.w,t1,b7); c7=fmaf(wB.w,t2,c7); d7=fmaf(wB.w,t3,d7); \
    FENCE }
#define S2ROWS(i, B) { LDROW10((B) + (i)*XSTR) FENCE \
    S2T(i,0,r0,r1,r2,r3) S2T(i,1,r1,r2,r3,r4) S2T(i,2,r2,r3,r4,r5) \
    S2T(i,3,r3,r4,r5,r6) S2T(i,4,r4,r5,r6,r7) S2T(i,5,r5,r6,r7,r8) \
    S2T(i,6,r6,r7,r8,r9) }
#define S2ALL(B) S2ROWS(0,B) S2ROWS(1,B) S2ROWS(2,B) S2ROWS(3,B) \
                 S2ROWS(4,B) S2ROWS(5,B) S2ROWS(6,B)

// ---------------------------------------------------------------------------
// One block per (channel, row-quarter): 2048 blocks x 256 threads.
// 4-px strips with ROW-STREAMED window (10 floats live, reloaded per pass)
// + per-row/per-tap sched fences -> peak liveness ~60-70 regs (no spill),
// while weight broadcasts amortize over 4 px. Op order identical to r10
// (which passed absmax 0): row-major k-ascending sum, then ascending-k
// sub-then-fma chains, filters ascending.
// ---------------------------------------------------------------------------
__global__ __launch_bounds__(256, 4) void stage_kernel(
    const float* __restrict__ x,    // [64][64][64]
    const float* __restrict__ W1,   // [49][8]
    const float* __restrict__ W2,   // [49][8]
    uint8_t* __restrict__ codes)    // [512][4096]
{
    __shared__ __align__(16) float xs[XROWS * XSTR];
    __shared__ __align__(16) float ms[MROWS * XSTR];
    __shared__ float w1s[PP];
    __shared__ __align__(16) float w2s[PP * 8];

    const int b    = blockIdx.x;
    const int ch   = b >> 2;
    const int q16  = (b & 3) * 16;
    const int l    = ch >> 6;
    const int img  = ch & 63;
    const int tid  = threadIdx.x;

    // stage weights into LDS (all threads cover all elements)
    if (tid < PP) w1s[tid] = W1[tid * 8 + l];
    #pragma unroll 1
    for (int i = tid; i < PP * 8; i += 256) w2s[i] = W2[i];

    // zero ms (stage-2 SAME padding: pad cols + out-of-image rows stay 0)
    #pragma unroll 1
    for (int i = tid; i < MROWS * XSTR; i += 256) ms[i] = 0.f;

    // load xs zero-padded (xs col c <-> x col c-3; xs row r <-> x row q16-6+r)
    const float* xb = x + (size_t)img * PIX;
    #pragma unroll 1
    for (int idx = tid; idx < XROWS * XSTR; idx += 256) {
        int r  = idx / XSTR, c = idx - r * XSTR;
        int gr = q16 - 6 + r, gc = c - 3;
        float v = 0.f;
        if (gr >= 0 && gr < IMG && gc >= 0 && gc < IMG)
            v = xb[gr * IMG + gc];
        xs[idx] = v;
    }
    __syncthreads();

    // ---- stage 1: 22 ms-rows x 16 col-strips = 352 strips (4 px each) ----
    #pragma unroll 1
    for (int it = 0; it < 2; ++it) {
        int s = tid + it * 256;
        if (s < MROWS * 16) {
            const int row = s >> 4;           // ms row 0..21
            const int cs4 = (s & 15) * 4;     // pixel col 0..60
            const float* bp = &xs[row * XSTR + cs4];
            DECLR
            float s0 = 0.f, s1 = 0.f, s2 = 0.f, s3 = 0.f;
            SUMALL(bp)
            const float mu0 = s0 / 49.0f, mu1 = s1 / 49.0f;
            const float mu2 = s2 / 49.0f, mu3 = s3 / 49.0f;
            float a0 = 0.f, a1 = 0.f, a2 = 0.f, a3 = 0.f;
            S1ALL(bp)
            const int gm = q16 - 3 + row;
            const bool in_img = (gm >= 0) && (gm < IMG);
            float* mp = &ms[row * XSTR + 3 + cs4];
            mp[0] = in_img ? a0 : 0.f;
            mp[1] = in_img ? a1 : 0.f;
            mp[2] = in_img ? a2 : 0.f;
            mp[3] = in_img ? a3 : 0.f;
        }
    }
    __syncthreads();

    // ---- stage 2 + code bits: 16 rows x 16 col-strips = 256 strips ----
    {
        const int rr  = tid >> 4;             // out row 0..15
        const int cs4 = (tid & 15) * 4;       // pixel col 0..60
        const float* bp = &ms[rr * XSTR + cs4];
        DECLR
        float s0 = 0.f, s1 = 0.f, s2 = 0.f, s3 = 0.f;
        SUMALL(bp)
        const float mu0 = s0 / 49.0f, mu1 = s1 / 49.0f;
        const float mu2 = s2 / 49.0f, mu3 = s3 / 49.0f;
        float a0=0.f,a1=0.f,a2=0.f,a3=0.f,a4=0.f,a5=0.f,a6=0.f,a7=0.f;
        float b0=0.f,b1=0.f,b2=0.f,b3=0.f,b4=0.f,b5=0.f,b6=0.f,b7=0.f;
        float c0=0.f,c1=0.f,c2=0.f,c3=0.f,c4=0.f,c5=0.f,c6=0.f,c7=0.f;
        float d0=0.f,d1=0.f,d2=0.f,d3=0.f,d4=0.f,d5=0.f,d6=0.f,d7=0.f;
        S2ALL(bp)
        uint32_t k0 = 0, k1 = 0, k2 = 0, k3 = 0;
        k0 |= (a0>0.f)?128u:0u; k1 |= (b0>0.f)?128u:0u; k2 |= (c0>0.f)?128u:0u; k3 |= (d0>0.f)?128u:0u;
        k0 |= (a1>0.f)? 64u:0u; k1 |= (b1>0.f)? 64u:0u; k2 |= (c1>0.f)? 64u:0u; k3 |= (d1>0.f)? 64u:0u;
        k0 |= (a2>0.f)? 32u:0u; k1 |= (b2>0.f)? 32u:0u; k2 |= (c2>0.f)? 32u:0u; k3 |= (d2>0.f)? 32u:0u;
        k0 |= (a3>0.f)? 16u:0u; k1 |= (b3>0.f)? 16u:0u; k2 |= (c3>0.f)? 16u:0u; k3 |= (d3>0.f)? 16u:0u;
        k0 |= (a4>0.f)?  8u:0u; k1 |= (b4>0.f)?  8u:0u; k2 |= (c4>0.f)?  8u:0u; k3 |= (d4>0.f)?  8u:0u;
        k0 |= (a5>0.f)?  4u:0u; k1 |= (b5>0.f)?  4u:0u; k2 |= (c5>0.f)?  4u:0u; k3 |= (d5>0.f)?  4u:0u;
        k0 |= (a6>0.f)?  2u:0u; k1 |= (b6>0.f)?  2u:0u; k2 |= (c6>0.f)?  2u:0u; k3 |= (d6>0.f)?  2u:0u;
        k0 |= (a7>0.f)?  1u:0u; k1 |= (b7>0.f)?  1u:0u; k2 |= (c7>0.f)?  1u:0u; k3 |= (d7>0.f)?  1u:0u;
        uint32_t packed = k0 | (k1 << 8) | (k2 << 16) | (k3 << 24);
        *(uint32_t*)(codes + (size_t)ch * PIX + (q16 + rr) * 64 + cs4) = packed;
    }
}

// ---------------------------------------------------------------------------
// Kernel B: histogram + entropy (unchanged, ~4 us)
// ---------------------------------------------------------------------------
#define CPB 32

__global__ __launch_bounds__(256) void hist_kernel(
    const uint8_t* __restrict__ codes,  // [512][4096]
    float* __restrict__ out)            // [49*256][512]
{
    __shared__ uint32_t hist[256 * 33];

    const int bid   = blockIdx.x;       // 0..783
    const int cgrp  = bid & 15;
    const int nb    = bid >> 4;         // 0..48
    const int bi    = nb / 7, bj = nb - bi * 7;
    const int tid   = threadIdx.x;
    const int cbase = cgrp * CPB;

    for (int i = tid; i < 256 * 33; i += 256) hist[i] = 0;
    __syncthreads();

    const int cl  = tid >> 3;           // 0..31
    const int sub = tid & 7;            // 0..7
    const uint8_t* cp = codes + (size_t)(cbase + cl) * PIX;
    #pragma unroll
    for (int rr = 0; rr < 2; ++rr) {
        int row = bi * 8 + (sub * 2 + rr);
        const uint8_t* rp = cp + row * 64 + bj * 8;
        uint64_t v0 = *(const uint64_t*)(rp);
        uint64_t v1 = *(const uint64_t*)(rp + 8);
        #pragma unroll
        for (int t = 0; t < 8; ++t)
            atomicAdd(&hist[(uint32_t)((v0 >> (8 * t)) & 255u) * 33 + cl], 1u);
        #pragma unroll
        for (int t = 0; t < 8; ++t)
            atomicAdd(&hist[(uint32_t)((v1 >> (8 * t)) & 255u) * 33 + cl], 1u);
    }
    __syncthreads();

    const int lane_c = tid & 31;
    const int bin0   = tid >> 5;        // 0..7
    for (int i = 0; i < 32; ++i) {
        int bin = i * 8 + bin0;
        uint32_t cnt = hist[bin * 33 + lane_c];
        float ent = 0.f;
        if (cnt > 0) {
            float pz = (float)cnt * (1.0f / 256.0f);
            ent = -pz * log2f(pz);
        }
        out[((size_t)(nb * 256 + bin)) * 512 + cbase + lane_c] = ent;
    }
}

extern "C" void kernel_launch(void* const* d_in, const int* in_sizes, int n_in,
                              void* d_out, int out_size, void* d_ws, size_t ws_size,
                              hipStream_t stream) {
    const float* x  = (const float*)d_in[0];
    const float* W1 = (const float*)d_in[1];
    const float* W2 = (const float*)d_in[2];
    float* out = (float*)d_out;
    uint8_t* codes = (uint8_t*)d_ws;   // 512*4096 = 2 MB

    stage_kernel<<<2048, 256, 0, stream>>>(x, W1, W2, codes);
    hist_kernel<<<784, 256, 0, stream>>>(codes, out);
}